// Round 24
// baseline (570.429 us; speedup 1.0000x reference)
//
#include <hip/hip_runtime.h>
#include <math.h>

#define B_ 8
#define N_ 2048
#define C_ 256
#define TOK (B_*N_)
#define T_ 64
#define NCH (N_/T_)   // 32 chunks per batch

typedef __bf16 bf16x8 __attribute__((ext_vector_type(8)));
typedef float f32x4v __attribute__((ext_vector_type(4)));

__device__ __forceinline__ float dot4(const float4& a, const float4& b) {
  return (a.x*b.x + a.y*b.y) + (a.z*b.z + a.w*b.w);
}
__device__ __forceinline__ float rdlane(float x, int idx) {
  return __int_as_float(__builtin_amdgcn_readlane(__float_as_int(x), idx));
}
__device__ __forceinline__ float bf2f(unsigned short u) {
  return __uint_as_float(((unsigned)u) << 16);
}
__device__ __forceinline__ unsigned short f2bf(float f) {
  unsigned x = __float_as_uint(f);
  return (unsigned short)((x + 0x7FFFu + ((x >> 16) & 1u)) >> 16);
}

// ---------------- bf16 hi/lo split, FRAGMENT-PACKED (R21 verbatim) ---------
__global__ __launch_bounds__(256) void split_pack(const float* __restrict__ src,
                                                  unsigned short* __restrict__ hi,
                                                  unsigned short* __restrict__ lo) {
  const size_t f = ((size_t)blockIdx.x * 256 + threadIdx.x) * 4;
  float4 v = *(const float4*)(src + f);
  const int row = (int)(f >> 8);
  const int k   = (int)(f & 255);
  const int R = row >> 4, lr = row & 15;
  const int ks = k >> 5, kg = (k >> 3) & 3, ki = k & 7;
  const size_t pos = ((((size_t)R*8 + ks)*64) + kg*16 + lr)*8 + ki;
  ushort4 H, L;
  H.x = f2bf(v.x); H.y = f2bf(v.y); H.z = f2bf(v.z); H.w = f2bf(v.w);
  L.x = f2bf(v.x - bf2f(H.x));
  L.y = f2bf(v.y - bf2f(H.y));
  L.z = f2bf(v.z - bf2f(H.z));
  L.w = f2bf(v.w - bf2f(H.w));
  *(ushort4*)(hi + pos) = H;
  *(ushort4*)(lo + pos) = L;
}

// ---------------- MFMA projection v3 (R21 verbatim) ------------------------
template<int EPI>  // 0 silu+l2norm, 1 silu, 2 sigmoid+mean, 3 bias-only
__global__ __launch_bounds__(256) void proj_v3(const unsigned short* __restrict__ xh,
                                               const unsigned short* __restrict__ xl,
                                               const unsigned short* __restrict__ wh,
                                               const unsigned short* __restrict__ wl,
                                               const float* __restrict__ bias,
                                               float* __restrict__ out) {
  __shared__ float redp[4][20];
  const int tid = threadIdx.x;
  const int l = tid & 63, w = tid >> 6;
  const int lc = l & 15, kg = l >> 4;
  const int rb = blockIdx.x * 16;
  const size_t Rbase = (size_t)blockIdx.x * 8;

  f32x4v acc[4];
  #pragma unroll
  for (int nt2 = 0; nt2 < 4; ++nt2) acc[nt2] = (f32x4v){0.f, 0.f, 0.f, 0.f};

  #pragma unroll
  for (int ks = 0; ks < 8; ++ks) {
    const size_t apos = ((Rbase + ks)*64 + l)*8;
    bf16x8 ah = *reinterpret_cast<const bf16x8*>(xh + apos);
    bf16x8 al = *reinterpret_cast<const bf16x8*>(xl + apos);
    #pragma unroll
    for (int nt2 = 0; nt2 < 4; ++nt2) {
      const size_t bpos = (((size_t)(w*4 + nt2)*8 + ks)*64 + l)*8;
      bf16x8 bh = *reinterpret_cast<const bf16x8*>(wh + bpos);
      bf16x8 bl = *reinterpret_cast<const bf16x8*>(wl + bpos);
      acc[nt2] = __builtin_amdgcn_mfma_f32_16x16x32_bf16(ah, bh, acc[nt2], 0, 0, 0);
      acc[nt2] = __builtin_amdgcn_mfma_f32_16x16x32_bf16(ah, bl, acc[nt2], 0, 0, 0);
      acc[nt2] = __builtin_amdgcn_mfma_f32_16x16x32_bf16(al, bh, acc[nt2], 0, 0, 0);
    }
  }

  const int row0 = kg * 4;

  if constexpr (EPI == 3) {
    #pragma unroll
    for (int nt2 = 0; nt2 < 4; ++nt2) {
      const float bval = bias[w*64 + nt2*16 + lc];
      #pragma unroll
      for (int e = 0; e < 4; ++e)
        out[(size_t)(rb + row0 + e)*C_ + w*64 + nt2*16 + lc] = acc[nt2][e] + bval;
    }
  } else if constexpr (EPI == 1) {
    #pragma unroll
    for (int nt2 = 0; nt2 < 4; ++nt2) {
      const float bval = bias[w*64 + nt2*16 + lc];
      #pragma unroll
      for (int e = 0; e < 4; ++e) {
        float y = acc[nt2][e] + bval;
        out[(size_t)(rb + row0 + e)*C_ + w*64 + nt2*16 + lc] = y / (1.f + __expf(-y));
      }
    }
  } else if constexpr (EPI == 0) {
    float part[4] = {0.f, 0.f, 0.f, 0.f};
    #pragma unroll
    for (int nt2 = 0; nt2 < 4; ++nt2) {
      const float bval = bias[w*64 + nt2*16 + lc];
      #pragma unroll
      for (int e = 0; e < 4; ++e) {
        float y = acc[nt2][e] + bval;
        float s = y / (1.f + __expf(-y));
        acc[nt2][e] = s;
        part[e] += s * s;
      }
    }
    #pragma unroll
    for (int e = 0; e < 4; ++e) {
      float r = part[e];
      r += __shfl_xor(r, 1, 64);
      r += __shfl_xor(r, 2, 64);
      r += __shfl_xor(r, 4, 64);
      r += __shfl_xor(r, 8, 64);
      part[e] = r;
    }
    if (lc == 0) {
      #pragma unroll
      for (int e = 0; e < 4; ++e) redp[w][row0 + e] = part[e];
    }
    __syncthreads();
    #pragma unroll
    for (int e = 0; e < 4; ++e) {
      float s = redp[0][row0+e] + redp[1][row0+e] + redp[2][row0+e] + redp[3][row0+e];
      part[e] = 1.f / (sqrtf(s) + 1e-6f);
    }
    #pragma unroll
    for (int nt2 = 0; nt2 < 4; ++nt2)
      #pragma unroll
      for (int e = 0; e < 4; ++e)
        out[(size_t)(rb + row0 + e)*C_ + w*64 + nt2*16 + lc] = acc[nt2][e] * part[e];
  } else {
    float part[4] = {0.f, 0.f, 0.f, 0.f};
    #pragma unroll
    for (int nt2 = 0; nt2 < 4; ++nt2) {
      const float bval = bias[w*64 + nt2*16 + lc];
      #pragma unroll
      for (int e = 0; e < 4; ++e) {
        float y = acc[nt2][e] + bval;
        part[e] += 1.f / (1.f + __expf(-y));
      }
    }
    #pragma unroll
    for (int e = 0; e < 4; ++e) {
      float r = part[e];
      r += __shfl_xor(r, 1, 64);
      r += __shfl_xor(r, 2, 64);
      r += __shfl_xor(r, 4, 64);
      r += __shfl_xor(r, 8, 64);
      part[e] = r;
    }
    if (lc == 0) {
      #pragma unroll
      for (int e = 0; e < 4; ++e) redp[w][row0 + e] = part[e];
    }
    __syncthreads();
    if (w == 0 && lc == 0) {
      #pragma unroll
      for (int e = 0; e < 4; ++e) {
        float s = redp[0][row0+e] + redp[1][row0+e] + redp[2][row0+e] + redp[3][row0+e];
        out[rb + row0 + e] = s * (1.f / 256.f);
      }
    }
  }
}

// ---------------- fused gram + WY solves + intra output --------------------
// R23 base. Change: Qtilde and O_intra no longer read Wl from LDS (was 2
// uniform+per-lane b128 per 8 FLOPs = 16.4k LDS ops/CU, the prep LDS-pipe
// bottleneck). Each wave-lane holds its ROW of Wl in 16 float4 registers
// (wX); Wl[t][s] comes from v_readlane (VALU pipe), and t-blocking by 8
// amortizes each u/y row b128 over 8 output rows (2048 -> 128 reads/pass).
// Omega scaling applied to wX in registers (Wl LDS stays raw; scale pass
// now only transforms Gl). Solves / gram / Z unchanged.
__global__ __launch_bounds__(256) void chunk_prep(const float* __restrict__ kn,
                                                  const float* __restrict__ qn,
                                                  float* __restrict__ vO,
                                                  const float* __restrict__ Ag,
                                                  const float* __restrict__ Bg,
                                                  float* __restrict__ Ubuf,
                                                  float* __restrict__ qrm,
                                                  float* __restrict__ gbuf,
                                                  float* __restrict__ Oout) {
  __shared__ float Gl[64][68];
  __shared__ float Wl[64][68];
  __shared__ float pool[17408];
  __shared__ float gam[64], al[64], bl[64];
  float* Kp = pool;
  float* Qp = pool + 4096;
  const int bid = blockIdx.x;
  const int b = bid & 7, c = bid >> 3;
  const size_t ct0 = (size_t)b*N_ + (size_t)c*T_;
  const size_t base = ct0 * C_;
  const int tid = threadIdx.x;
  const int lane = tid & 63;
  const int sg = tid >> 6;

  if (tid < 64) { al[tid] = Ag[ct0 + tid]; bl[tid] = Bg[ct0 + tid]; }

  float accG[16], accQ[16];
  #pragma unroll
  for (int m = 0; m < 16; ++m) { accG[m] = 0.f; accQ[m] = 0.f; }
  for (int p = 0; p < 4; ++p) {
    __syncthreads();
    #pragma unroll
    for (int i = 0; i < 4; ++i) {
      int idx = i*256 + tid;
      int t = idx >> 4, u = idx & 15;
      int phys = (t*16 + (u ^ (t & 15))) * 4;
      *(float4*)&Kp[phys] = *(const float4*)(kn + base + (size_t)t*C_ + p*64 + u*4);
      *(float4*)&Qp[phys] = *(const float4*)(qn + base + (size_t)t*C_ + p*64 + u*4);
    }
    __syncthreads();
    #pragma unroll 4
    for (int j4 = 0; j4 < 16; ++j4) {
      float4 kt = *(const float4*)&Kp[(lane*16 + (j4 ^ (lane & 15))) * 4];
      float4 qt = *(const float4*)&Qp[(lane*16 + (j4 ^ (lane & 15))) * 4];
      #pragma unroll
      for (int m = 0; m < 16; ++m) {
        int r = sg*16 + m;
        float4 ks = *(const float4*)&Kp[(r*16 + (j4 ^ (r & 15))) * 4];
        accG[m] += dot4(kt, ks);
        accQ[m] += dot4(qt, ks);
      }
    }
  }
  __syncthreads();
  #pragma unroll
  for (int m = 0; m < 16; ++m) {
    int col = sg*16 + m;
    Gl[lane][col] = (col <  lane) ? accG[m] : 0.f;
    Wl[lane][col] = (col <= lane) ? accQ[m] : 0.f;
  }
  __syncthreads();
  if (tid == 0) {
    float g = 1.f;
    for (int s = 0; s < 64; ++s) { g *= al[s]; gam[s] = g; }
  }
  __syncthreads();
  if (tid < 64) gbuf[ct0 + tid] = gam[tid];
  __syncthreads();   // gram reads of pool done before rows overwrite it

  const int j = tid;
  const int jx = j & 15;
  const int jb = j * 16;   // float4-unit base of this thread's row

  // zero-init row (16 swizzled float4 groups)
  #pragma unroll
  for (int g = 0; g < 16; ++g)
    *(float4*)&pool[(jb + (g ^ jx)) * 4] = make_float4(0.f, 0.f, 0.f, 0.f);

  // ---- U solve (state in swizzled LDS row; runtime loops; unchanged) ----
  for (int s = 0; s < 64; ++s) {
    float a0 = kn[base + (size_t)s*C_ + j], a1 = 0.f, a2 = 0.f, a3 = 0.f;
    for (int r4 = 0; r4 <= (s >> 2); ++r4) {
      float4 g = *(const float4*)&Gl[s][r4*4];
      float4 uu = *(const float4*)&pool[(jb + (r4 ^ jx)) * 4];
      a0 -= g.x*uu.x; a1 -= g.y*uu.y; a2 -= g.z*uu.z; a3 -= g.w*uu.w;
    }
    float us = bl[s] * ((a0 + a1) + (a2 + a3));
    pool[(jb + ((s >> 2) ^ jx)) * 4 + (s & 3)] = us;
    Ubuf[base + (size_t)s*C_ + j] = us;
  }

  // ---- Qtilde: wX registers + readlane, t-blocked by 8 ----
  {
    float4 wX[16];
    #pragma unroll
    for (int s4 = 0; s4 < 16; ++s4) wX[s4] = *(const float4*)&Wl[lane][s4*4];
    for (int tb = 0; tb < 8; ++tb) {
      float acc[8];
      #pragma unroll
      for (int i = 0; i < 8; ++i)
        acc[i] = qn[base + (size_t)(tb*8 + i)*C_ + j];
      #pragma unroll
      for (int s4 = 0; s4 < 16; ++s4) {
        float4 uu = *(const float4*)&pool[(jb + (s4 ^ jx)) * 4];
        #pragma unroll
        for (int i = 0; i < 8; ++i) {
          const int t = tb*8 + i;
          acc[i] -= rdlane(wX[s4].x, t) * uu.x
                  + rdlane(wX[s4].y, t) * uu.y
                  + rdlane(wX[s4].z, t) * uu.z
                  + rdlane(wX[s4].w, t) * uu.w;
        }
      }
      #pragma unroll
      for (int i = 0; i < 8; ++i)
        qrm[base + (size_t)(tb*8 + i)*C_ + j] = acc[i];
    }
  }

  // ---- scale: Gl -> Ghat only (Wl stays raw; Omega applied in regs) ----
  __syncthreads();
  #pragma unroll
  for (int p2 = 0; p2 < 16; ++p2) {
    int idx = p2*256 + tid; int s = idx >> 6, r = idx & 63;
    Gl[s][r] *= gam[s] / gam[r];
  }
  __syncthreads();
  const float gT = gam[63];

  // ---- Y solve (unchanged; reuses row) ----
  for (int s = 0; s < 64; ++s) {
    float a0 = vO[base + (size_t)s*C_ + j], a1 = 0.f, a2 = 0.f, a3 = 0.f;
    for (int r4 = 0; r4 <= (s >> 2); ++r4) {
      float4 g = *(const float4*)&Gl[s][r4*4];
      float4 yy = *(const float4*)&pool[(jb + (r4 ^ jx)) * 4];
      a0 -= g.x*yy.x; a1 -= g.y*yy.y; a2 -= g.z*yy.z; a3 -= g.w*yy.w;
    }
    pool[(jb + ((s >> 2) ^ jx)) * 4 + (s & 3)] = bl[s] * ((a0 + a1) + (a2 + a3));
  }
  __syncthreads();   // all vO chunk reads done (also y rows complete)
  for (int s4 = 0; s4 < 16; ++s4) {
    float4 yy = *(const float4*)&pool[(jb + (s4 ^ jx)) * 4];
    float z0 = (gT / gam[s4*4+0]) * yy.x;
    float z1 = (gT / gam[s4*4+1]) * yy.y;
    float z2 = (gT / gam[s4*4+2]) * yy.z;
    float z3 = (gT / gam[s4*4+3]) * yy.w;
    *(float4*)&vO[base + (size_t)j*64 + s4*4] = make_float4(z0, z1, z2, z3);  // Z^T [i][s]
  }

  // ---- O_intra: reload wX, scale to Omega in regs, t-blocked by 8 ----
  {
    const float gaml = gam[lane];            // gam[t] for this lane's row
    float4 wX[16];
    #pragma unroll
    for (int s4 = 0; s4 < 16; ++s4) {
      float4 wv = *(const float4*)&Wl[lane][s4*4];
      wv.x *= gaml / gam[s4*4+0];
      wv.y *= gaml / gam[s4*4+1];
      wv.z *= gaml / gam[s4*4+2];
      wv.w *= gaml / gam[s4*4+3];
      wX[s4] = wv;                           // Omega[lane][s]
    }
    for (int tb = 0; tb < 8; ++tb) {
      float acc[8];
      #pragma unroll
      for (int i = 0; i < 8; ++i) acc[i] = 0.f;
      #pragma unroll
      for (int s4 = 0; s4 < 16; ++s4) {
        float4 yy = *(const float4*)&pool[(jb + (s4 ^ jx)) * 4];
        #pragma unroll
        for (int i = 0; i < 8; ++i) {
          const int t = tb*8 + i;
          acc[i] += rdlane(wX[s4].x, t) * yy.x
                  + rdlane(wX[s4].y, t) * yy.y
                  + rdlane(wX[s4].z, t) * yy.z
                  + rdlane(wX[s4].w, t) * yy.w;
        }
      }
      #pragma unroll
      for (int i = 0; i < 8; ++i)
        Oout[base + (size_t)(tb*8 + i)*C_ + j] = acc[i];
    }
  }
}

// ---------------- serial chunk scan v4 (R22 verbatim) ----------------------
__global__ __launch_bounds__(512) void chunk_scan(const float* __restrict__ kn,
                                                  const float* __restrict__ qrm,
                                                  const float* __restrict__ urm,
                                                  const float* __restrict__ ztT,
                                                  const float* __restrict__ gbuf,
                                                  float* __restrict__ Oout) {
  __shared__ float Qs[16384];
  __shared__ float Us[16384];
  __shared__ float red[8*64*12];
  const int bid = blockIdx.x;
  const int b = bid & 7;
  const int wgrp = bid >> 3;
  const int tid = threadIdx.x;
  const int wave = tid >> 6, lane = tid & 63;
  const int half = wave >> 2, jq = wave & 3;
  const int i0h = wgrp*8 + half*4;
  const int lx = lane & 15;

  float S_[4];
  #pragma unroll
  for (int r = 0; r < 4; ++r) S_[r] = 0.f;

  for (int ch = 0; ch < NCH; ++ch) {
    const size_t ct0 = (size_t)b*N_ + (size_t)ch*T_;
    const size_t base = ct0 * C_;

    #pragma unroll
    for (int i = 0; i < 8; ++i) {
      int g = i*512 + tid;
      int t = g >> 6, u = g & 63;
      int phys = (t*64 + (u ^ (t & 15))) * 4;
      *(float4*)&Qs[phys] = *(const float4*)(qrm + base + (size_t)g*4);
      *(float4*)&Us[phys] = *(const float4*)(urm + base + (size_t)g*4);
    }
    __syncthreads();                               // B1

    const float gv = gbuf[ct0 + lane];
    const float gT = rdlane(gv, 63);

    float oA[4], dB[4];
    #pragma unroll
    for (int r = 0; r < 4; ++r) { oA[r] = 0.f; dB[r] = 0.f; }
    #pragma unroll
    for (int uu = 0; uu < 16; ++uu) {
      const int u = (jq << 4) + uu;
      float4 qv = *(const float4*)&Qs[(lane*64 + (u ^ lx)) * 4];
      float4 uv = *(const float4*)&Us[(lane*64 + (u ^ lx)) * 4];
      #pragma unroll
      for (int m = 0; m < 4; ++m) {
        const int jl = 4*uu + m;
        const float qm = (m==0) ? qv.x : (m==1) ? qv.y : (m==2) ? qv.z : qv.w;
        const float um = (m==0) ? uv.x : (m==1) ? uv.y : (m==2) ? uv.z : uv.w;
        #pragma unroll
        for (int r = 0; r < 4; ++r) {
          const float sv = rdlane(S_[r], jl);
          oA[r] += sv * qm;
          dB[r] += sv * um;
        }
      }
    }
    {
      float* rp = &red[(wave*64 + lane) * 12];
      *(float4*)&rp[0] = make_float4(oA[0], oA[1], oA[2], oA[3]);
      *(float4*)&rp[4] = make_float4(dB[0], dB[1], dB[2], dB[3]);
    }
    __syncthreads();                               // B2

    #pragma unroll
    for (int i = 0; i < 8; ++i) {
      int idx = (i*512 + tid) * 4;
      *(float4*)&Qs[idx] = *(const float4*)(kn + base + idx);
    }

    #pragma unroll
    for (int r = 0; r < 4; ++r) { oA[r] = 0.f; dB[r] = 0.f; }
    #pragma unroll
    for (int jq2 = 0; jq2 < 4; ++jq2) {
      const float* rp = &red[((half*4 + jq2)*64 + lane) * 12];
      float4 a = *(const float4*)&rp[0];
      float4 d = *(const float4*)&rp[4];
      oA[0] += a.x; oA[1] += a.y; oA[2] += a.z; oA[3] += a.w;
      dB[0] += d.x; dB[1] += d.y; dB[2] += d.z; dB[3] += d.w;
    }
    #pragma unroll
    for (int r = 0; r < 4; ++r) {
      const float z = ztT[base + (size_t)(i0h + r)*64 + lane];
      dB[r] = gT*dB[r] - z;
    }
    if (jq == 0) {
      float* orow = Oout + base + (size_t)lane*C_ + i0h;
      float4 o0 = *(float4*)&orow[0];
      o0.x += gv*oA[0]; o0.y += gv*oA[1]; o0.z += gv*oA[2]; o0.w += gv*oA[3];
      *(float4*)&orow[0] = o0;
    }
    __syncthreads();                               // B3

    float acc[4];
    #pragma unroll
    for (int r = 0; r < 4; ++r) acc[r] = 0.f;
    const int jcol = (jq << 6) + lane;
    #pragma unroll 8
    for (int s = 0; s < 64; ++s) {
      const float kv = Qs[s*256 + jcol];
      #pragma unroll
      for (int r = 0; r < 4; ++r)
        acc[r] += rdlane(dB[r], s) * kv;
    }
    #pragma unroll
    for (int r = 0; r < 4; ++r) S_[r] = gT*S_[r] - acc[r];
    __syncthreads();                               // B4
  }
}

extern "C" void kernel_launch(void* const* d_in, const int* in_sizes, int n_in,
                              void* d_out, int out_size, void* d_ws, size_t ws_size,
                              hipStream_t stream) {
  const float* x  = (const float*)d_in[0];
  const float* Wq = (const float*)d_in[1];  const float* bq = (const float*)d_in[2];
  const float* Wk = (const float*)d_in[3];  const float* bk = (const float*)d_in[4];
  const float* Wv = (const float*)d_in[5];  const float* bv = (const float*)d_in[6];
  const float* Wa = (const float*)d_in[7];  const float* ba = (const float*)d_in[8];
  const float* Wb = (const float*)d_in[9];  const float* bb = (const float*)d_in[10];
  const float* Wo = (const float*)d_in[11]; const float* bo = (const float*)d_in[12];

  float* ws = (float*)d_ws;
  const size_t TC = (size_t)TOK * C_;
  float* qn   = ws;
  float* kn   = ws + TC;
  float* vO   = ws + 2*TC;             // V -> Z^T [i][s] (in place)
  float* Ag   = ws + 3*TC;
  float* Bg   = Ag + TOK;
  float* gbuf = Bg + TOK;
  float* Ubuf = gbuf + TOK;            // x-splits -> U -> Wo-splits
  float* qrm  = Ubuf + TC;             // Qtilde -> O-splits

  unsigned short* xhi = (unsigned short*)Ubuf;
  unsigned short* xlo = xhi + TC;
  unsigned short* whd = (unsigned short*)d_out;
  unsigned short* whiU = (unsigned short*)Ubuf;
  unsigned short* wloU = whiU + 65536;
  unsigned short* ohi = (unsigned short*)qrm;
  unsigned short* olo = ohi + TC;

  split_pack<<<dim3(TC/1024), 256, 0, stream>>>(x, xhi, xlo);
  split_pack<<<dim3(64), 256, 0, stream>>>(Wq, whd + 0*131072, whd + 0*131072 + 65536);
  split_pack<<<dim3(64), 256, 0, stream>>>(Wk, whd + 1*131072, whd + 1*131072 + 65536);
  split_pack<<<dim3(64), 256, 0, stream>>>(Wv, whd + 2*131072, whd + 2*131072 + 65536);
  split_pack<<<dim3(64), 256, 0, stream>>>(Wa, whd + 3*131072, whd + 3*131072 + 65536);
  split_pack<<<dim3(64), 256, 0, stream>>>(Wb, whd + 4*131072, whd + 4*131072 + 65536);
  proj_v3<0><<<dim3(TOK/16), 256, 0, stream>>>(xhi, xlo, whd + 0*131072, whd + 0*131072 + 65536, bq, qn);
  proj_v3<0><<<dim3(TOK/16), 256, 0, stream>>>(xhi, xlo, whd + 1*131072, whd + 1*131072 + 65536, bk, kn);
  proj_v3<1><<<dim3(TOK/16), 256, 0, stream>>>(xhi, xlo, whd + 2*131072, whd + 2*131072 + 65536, bv, vO);
  proj_v3<2><<<dim3(TOK/16), 256, 0, stream>>>(xhi, xlo, whd + 3*131072, whd + 3*131072 + 65536, ba, Ag);
  proj_v3<2><<<dim3(TOK/16), 256, 0, stream>>>(xhi, xlo, whd + 4*131072, whd + 4*131072 + 65536, bb, Bg);
  chunk_prep<<<dim3(256), 256, 0, stream>>>(kn, qn, vO, Ag, Bg, Ubuf, qrm, gbuf,
                                            (float*)d_out);
  chunk_scan<<<dim3(256), 512, 0, stream>>>(kn, qrm, Ubuf, vO, gbuf,
                                            (float*)d_out);
  split_pack<<<dim3(64), 256, 0, stream>>>(Wo, whiU, wloU);
  split_pack<<<dim3(TC/1024), 256, 0, stream>>>((const float*)d_out, ohi, olo);
  proj_v3<3><<<dim3(TOK/16), 256, 0, stream>>>(ohi, olo, whiU, wloU, bo,
                                               (float*)d_out);
}

// Round 25
// 524.011 us; speedup vs baseline: 1.0886x; 1.0886x over previous
//
#include <hip/hip_runtime.h>
#include <math.h>

#define B_ 8
#define N_ 2048
#define C_ 256
#define TOK (B_*N_)
#define T_ 64
#define NCH (N_/T_)   // 32 chunks per batch

typedef __bf16 bf16x8 __attribute__((ext_vector_type(8)));
typedef float f32x4v __attribute__((ext_vector_type(4)));

__device__ __forceinline__ float dot4(const float4& a, const float4& b) {
  return (a.x*b.x + a.y*b.y) + (a.z*b.z + a.w*b.w);
}
__device__ __forceinline__ float rdlane(float x, int idx) {
  return __int_as_float(__builtin_amdgcn_readlane(__float_as_int(x), idx));
}
__device__ __forceinline__ float bf2f(unsigned short u) {
  return __uint_as_float(((unsigned)u) << 16);
}
__device__ __forceinline__ unsigned short f2bf(float f) {
  unsigned x = __float_as_uint(f);
  return (unsigned short)((x + 0x7FFFu + ((x >> 16) & 1u)) >> 16);
}

// ---------------- bf16 hi/lo split, FRAGMENT-PACKED (R21 verbatim) ---------
__global__ __launch_bounds__(256) void split_pack(const float* __restrict__ src,
                                                  unsigned short* __restrict__ hi,
                                                  unsigned short* __restrict__ lo) {
  const size_t f = ((size_t)blockIdx.x * 256 + threadIdx.x) * 4;
  float4 v = *(const float4*)(src + f);
  const int row = (int)(f >> 8);
  const int k   = (int)(f & 255);
  const int R = row >> 4, lr = row & 15;
  const int ks = k >> 5, kg = (k >> 3) & 3, ki = k & 7;
  const size_t pos = ((((size_t)R*8 + ks)*64) + kg*16 + lr)*8 + ki;
  ushort4 H, L;
  H.x = f2bf(v.x); H.y = f2bf(v.y); H.z = f2bf(v.z); H.w = f2bf(v.w);
  L.x = f2bf(v.x - bf2f(H.x));
  L.y = f2bf(v.y - bf2f(H.y));
  L.z = f2bf(v.z - bf2f(H.z));
  L.w = f2bf(v.w - bf2f(H.w));
  *(ushort4*)(hi + pos) = H;
  *(ushort4*)(lo + pos) = L;
}

// ---------------- MFMA projection v3 (R21 verbatim) ------------------------
template<int EPI>  // 0 silu+l2norm, 1 silu, 2 sigmoid+mean, 3 bias-only
__global__ __launch_bounds__(256) void proj_v3(const unsigned short* __restrict__ xh,
                                               const unsigned short* __restrict__ xl,
                                               const unsigned short* __restrict__ wh,
                                               const unsigned short* __restrict__ wl,
                                               const float* __restrict__ bias,
                                               float* __restrict__ out) {
  __shared__ float redp[4][20];
  const int tid = threadIdx.x;
  const int l = tid & 63, w = tid >> 6;
  const int lc = l & 15, kg = l >> 4;
  const int rb = blockIdx.x * 16;
  const size_t Rbase = (size_t)blockIdx.x * 8;

  f32x4v acc[4];
  #pragma unroll
  for (int nt2 = 0; nt2 < 4; ++nt2) acc[nt2] = (f32x4v){0.f, 0.f, 0.f, 0.f};

  #pragma unroll
  for (int ks = 0; ks < 8; ++ks) {
    const size_t apos = ((Rbase + ks)*64 + l)*8;
    bf16x8 ah = *reinterpret_cast<const bf16x8*>(xh + apos);
    bf16x8 al = *reinterpret_cast<const bf16x8*>(xl + apos);
    #pragma unroll
    for (int nt2 = 0; nt2 < 4; ++nt2) {
      const size_t bpos = (((size_t)(w*4 + nt2)*8 + ks)*64 + l)*8;
      bf16x8 bh = *reinterpret_cast<const bf16x8*>(wh + bpos);
      bf16x8 bl = *reinterpret_cast<const bf16x8*>(wl + bpos);
      acc[nt2] = __builtin_amdgcn_mfma_f32_16x16x32_bf16(ah, bh, acc[nt2], 0, 0, 0);
      acc[nt2] = __builtin_amdgcn_mfma_f32_16x16x32_bf16(ah, bl, acc[nt2], 0, 0, 0);
      acc[nt2] = __builtin_amdgcn_mfma_f32_16x16x32_bf16(al, bh, acc[nt2], 0, 0, 0);
    }
  }

  const int row0 = kg * 4;

  if constexpr (EPI == 3) {
    #pragma unroll
    for (int nt2 = 0; nt2 < 4; ++nt2) {
      const float bval = bias[w*64 + nt2*16 + lc];
      #pragma unroll
      for (int e = 0; e < 4; ++e)
        out[(size_t)(rb + row0 + e)*C_ + w*64 + nt2*16 + lc] = acc[nt2][e] + bval;
    }
  } else if constexpr (EPI == 1) {
    #pragma unroll
    for (int nt2 = 0; nt2 < 4; ++nt2) {
      const float bval = bias[w*64 + nt2*16 + lc];
      #pragma unroll
      for (int e = 0; e < 4; ++e) {
        float y = acc[nt2][e] + bval;
        out[(size_t)(rb + row0 + e)*C_ + w*64 + nt2*16 + lc] = y / (1.f + __expf(-y));
      }
    }
  } else if constexpr (EPI == 0) {
    float part[4] = {0.f, 0.f, 0.f, 0.f};
    #pragma unroll
    for (int nt2 = 0; nt2 < 4; ++nt2) {
      const float bval = bias[w*64 + nt2*16 + lc];
      #pragma unroll
      for (int e = 0; e < 4; ++e) {
        float y = acc[nt2][e] + bval;
        float s = y / (1.f + __expf(-y));
        acc[nt2][e] = s;
        part[e] += s * s;
      }
    }
    #pragma unroll
    for (int e = 0; e < 4; ++e) {
      float r = part[e];
      r += __shfl_xor(r, 1, 64);
      r += __shfl_xor(r, 2, 64);
      r += __shfl_xor(r, 4, 64);
      r += __shfl_xor(r, 8, 64);
      part[e] = r;
    }
    if (lc == 0) {
      #pragma unroll
      for (int e = 0; e < 4; ++e) redp[w][row0 + e] = part[e];
    }
    __syncthreads();
    #pragma unroll
    for (int e = 0; e < 4; ++e) {
      float s = redp[0][row0+e] + redp[1][row0+e] + redp[2][row0+e] + redp[3][row0+e];
      part[e] = 1.f / (sqrtf(s) + 1e-6f);
    }
    #pragma unroll
    for (int nt2 = 0; nt2 < 4; ++nt2)
      #pragma unroll
      for (int e = 0; e < 4; ++e)
        out[(size_t)(rb + row0 + e)*C_ + w*64 + nt2*16 + lc] = acc[nt2][e] * part[e];
  } else {
    float part[4] = {0.f, 0.f, 0.f, 0.f};
    #pragma unroll
    for (int nt2 = 0; nt2 < 4; ++nt2) {
      const float bval = bias[w*64 + nt2*16 + lc];
      #pragma unroll
      for (int e = 0; e < 4; ++e) {
        float y = acc[nt2][e] + bval;
        part[e] += 1.f / (1.f + __expf(-y));
      }
    }
    #pragma unroll
    for (int e = 0; e < 4; ++e) {
      float r = part[e];
      r += __shfl_xor(r, 1, 64);
      r += __shfl_xor(r, 2, 64);
      r += __shfl_xor(r, 4, 64);
      r += __shfl_xor(r, 8, 64);
      part[e] = r;
    }
    if (lc == 0) {
      #pragma unroll
      for (int e = 0; e < 4; ++e) redp[w][row0 + e] = part[e];
    }
    __syncthreads();
    if (w == 0 && lc == 0) {
      #pragma unroll
      for (int e = 0; e < 4; ++e) {
        float s = redp[0][row0+e] + redp[1][row0+e] + redp[2][row0+e] + redp[3][row0+e];
        out[rb + row0 + e] = s * (1.f / 256.f);
      }
    }
  }
}

// ---------------- fused gram + WY solves + intra output --------------------
// R24 base; solves restructured to BLOCKED RANK-4 forward substitution:
//  - kn / vO columns PRELOADED into the thread's pool row (64 batched
//    coalesced loads) -> removes the per-step serial global-load stall.
//  - per 4-step block: tiny serial 4x4 micro-solve (diagonal G block),
//    then a rank-4 update of the remaining rows whose iterations are
//    fully independent (pipelineable) -> serialization points 64 -> 16.
// Gram / Qtilde / O_intra / Z / scale unchanged (R24).
__global__ __launch_bounds__(256) void chunk_prep(const float* __restrict__ kn,
                                                  const float* __restrict__ qn,
                                                  float* __restrict__ vO,
                                                  const float* __restrict__ Ag,
                                                  const float* __restrict__ Bg,
                                                  float* __restrict__ Ubuf,
                                                  float* __restrict__ qrm,
                                                  float* __restrict__ gbuf,
                                                  float* __restrict__ Oout) {
  __shared__ float Gl[64][68];
  __shared__ float Wl[64][68];
  __shared__ float pool[17408];
  __shared__ float gam[64], al[64], bl[64];
  float* Kp = pool;
  float* Qp = pool + 4096;
  const int bid = blockIdx.x;
  const int b = bid & 7, c = bid >> 3;
  const size_t ct0 = (size_t)b*N_ + (size_t)c*T_;
  const size_t base = ct0 * C_;
  const int tid = threadIdx.x;
  const int lane = tid & 63;
  const int sg = tid >> 6;

  if (tid < 64) { al[tid] = Ag[ct0 + tid]; bl[tid] = Bg[ct0 + tid]; }

  float accG[16], accQ[16];
  #pragma unroll
  for (int m = 0; m < 16; ++m) { accG[m] = 0.f; accQ[m] = 0.f; }
  for (int p = 0; p < 4; ++p) {
    __syncthreads();
    #pragma unroll
    for (int i = 0; i < 4; ++i) {
      int idx = i*256 + tid;
      int t = idx >> 4, u = idx & 15;
      int phys = (t*16 + (u ^ (t & 15))) * 4;
      *(float4*)&Kp[phys] = *(const float4*)(kn + base + (size_t)t*C_ + p*64 + u*4);
      *(float4*)&Qp[phys] = *(const float4*)(qn + base + (size_t)t*C_ + p*64 + u*4);
    }
    __syncthreads();
    #pragma unroll 4
    for (int j4 = 0; j4 < 16; ++j4) {
      float4 kt = *(const float4*)&Kp[(lane*16 + (j4 ^ (lane & 15))) * 4];
      float4 qt = *(const float4*)&Qp[(lane*16 + (j4 ^ (lane & 15))) * 4];
      #pragma unroll
      for (int m = 0; m < 16; ++m) {
        int r = sg*16 + m;
        float4 ks = *(const float4*)&Kp[(r*16 + (j4 ^ (r & 15))) * 4];
        accG[m] += dot4(kt, ks);
        accQ[m] += dot4(qt, ks);
      }
    }
  }
  __syncthreads();
  #pragma unroll
  for (int m = 0; m < 16; ++m) {
    int col = sg*16 + m;
    Gl[lane][col] = (col <  lane) ? accG[m] : 0.f;
    Wl[lane][col] = (col <= lane) ? accQ[m] : 0.f;
  }
  __syncthreads();
  if (tid == 0) {
    float g = 1.f;
    for (int s = 0; s < 64; ++s) { g *= al[s]; gam[s] = g; }
  }
  __syncthreads();
  if (tid < 64) gbuf[ct0 + tid] = gam[tid];
  __syncthreads();   // gram reads of pool done before rows overwrite it

  const int j = tid;
  const int jx = j & 15;
  const int jb = j * 16;   // float4-unit base of this thread's row

  // ---- U solve: preload kn column, blocked rank-4 substitution ----
  #pragma unroll
  for (int s4 = 0; s4 < 16; ++s4) {
    float4 kv;
    kv.x = kn[base + (size_t)(s4*4+0)*C_ + j];
    kv.y = kn[base + (size_t)(s4*4+1)*C_ + j];
    kv.z = kn[base + (size_t)(s4*4+2)*C_ + j];
    kv.w = kn[base + (size_t)(s4*4+3)*C_ + j];
    *(float4*)&pool[(jb + (s4 ^ jx)) * 4] = kv;
  }
  for (int bq = 0; bq < 16; ++bq) {
    const int s0 = bq * 4;
    float4 a = *(const float4*)&pool[(jb + (bq ^ jx)) * 4];
    float4 g1 = *(const float4*)&Gl[s0+1][s0];
    float4 g2 = *(const float4*)&Gl[s0+2][s0];
    float4 g3 = *(const float4*)&Gl[s0+3][s0];
    float u0 = bl[s0+0] * a.x;
    float u1 = bl[s0+1] * (a.y - g1.x*u0);
    float u2 = bl[s0+2] * (a.z - g2.x*u0 - g2.y*u1);
    float u3 = bl[s0+3] * (a.w - g3.x*u0 - g3.y*u1 - g3.z*u2);
    *(float4*)&pool[(jb + (bq ^ jx)) * 4] = make_float4(u0, u1, u2, u3);
    Ubuf[base + (size_t)(s0+0)*C_ + j] = u0;
    Ubuf[base + (size_t)(s0+1)*C_ + j] = u1;
    Ubuf[base + (size_t)(s0+2)*C_ + j] = u2;
    Ubuf[base + (size_t)(s0+3)*C_ + j] = u3;
    for (int g = bq + 1; g < 16; ++g) {   // independent rank-4 updates
      float4 acc4 = *(const float4*)&pool[(jb + (g ^ jx)) * 4];
      float4 ga = *(const float4*)&Gl[4*g+0][s0];
      float4 gb = *(const float4*)&Gl[4*g+1][s0];
      float4 gc = *(const float4*)&Gl[4*g+2][s0];
      float4 gd = *(const float4*)&Gl[4*g+3][s0];
      acc4.x -= ga.x*u0 + ga.y*u1 + ga.z*u2 + ga.w*u3;
      acc4.y -= gb.x*u0 + gb.y*u1 + gb.z*u2 + gb.w*u3;
      acc4.z -= gc.x*u0 + gc.y*u1 + gc.z*u2 + gc.w*u3;
      acc4.w -= gd.x*u0 + gd.y*u1 + gd.z*u2 + gd.w*u3;
      *(float4*)&pool[(jb + (g ^ jx)) * 4] = acc4;
    }
  }

  // ---- Qtilde: wX registers + readlane, t-blocked by 8 (R24) ----
  {
    float4 wX[16];
    #pragma unroll
    for (int s4 = 0; s4 < 16; ++s4) wX[s4] = *(const float4*)&Wl[lane][s4*4];
    for (int tb = 0; tb < 8; ++tb) {
      float acc[8];
      #pragma unroll
      for (int i = 0; i < 8; ++i)
        acc[i] = qn[base + (size_t)(tb*8 + i)*C_ + j];
      #pragma unroll
      for (int s4 = 0; s4 < 16; ++s4) {
        float4 uu = *(const float4*)&pool[(jb + (s4 ^ jx)) * 4];
        #pragma unroll
        for (int i = 0; i < 8; ++i) {
          const int t = tb*8 + i;
          acc[i] -= rdlane(wX[s4].x, t) * uu.x
                  + rdlane(wX[s4].y, t) * uu.y
                  + rdlane(wX[s4].z, t) * uu.z
                  + rdlane(wX[s4].w, t) * uu.w;
        }
      }
      #pragma unroll
      for (int i = 0; i < 8; ++i)
        qrm[base + (size_t)(tb*8 + i)*C_ + j] = acc[i];
    }
  }

  // ---- scale: Gl -> Ghat only ----
  __syncthreads();
  #pragma unroll
  for (int p2 = 0; p2 < 16; ++p2) {
    int idx = p2*256 + tid; int s = idx >> 6, r = idx & 63;
    Gl[s][r] *= gam[s] / gam[r];
  }
  __syncthreads();
  const float gT = gam[63];

  // ---- Y solve: preload vO column, blocked rank-4 substitution ----
  #pragma unroll
  for (int s4 = 0; s4 < 16; ++s4) {
    float4 vv;
    vv.x = vO[base + (size_t)(s4*4+0)*C_ + j];
    vv.y = vO[base + (size_t)(s4*4+1)*C_ + j];
    vv.z = vO[base + (size_t)(s4*4+2)*C_ + j];
    vv.w = vO[base + (size_t)(s4*4+3)*C_ + j];
    *(float4*)&pool[(jb + (s4 ^ jx)) * 4] = vv;
  }
  for (int bq = 0; bq < 16; ++bq) {
    const int s0 = bq * 4;
    float4 a = *(const float4*)&pool[(jb + (bq ^ jx)) * 4];
    float4 g1 = *(const float4*)&Gl[s0+1][s0];
    float4 g2 = *(const float4*)&Gl[s0+2][s0];
    float4 g3 = *(const float4*)&Gl[s0+3][s0];
    float y0 = bl[s0+0] * a.x;
    float y1 = bl[s0+1] * (a.y - g1.x*y0);
    float y2 = bl[s0+2] * (a.z - g2.x*y0 - g2.y*y1);
    float y3 = bl[s0+3] * (a.w - g3.x*y0 - g3.y*y1 - g3.z*y2);
    *(float4*)&pool[(jb + (bq ^ jx)) * 4] = make_float4(y0, y1, y2, y3);
    for (int g = bq + 1; g < 16; ++g) {
      float4 acc4 = *(const float4*)&pool[(jb + (g ^ jx)) * 4];
      float4 ga = *(const float4*)&Gl[4*g+0][s0];
      float4 gb = *(const float4*)&Gl[4*g+1][s0];
      float4 gc = *(const float4*)&Gl[4*g+2][s0];
      float4 gd = *(const float4*)&Gl[4*g+3][s0];
      acc4.x -= ga.x*y0 + ga.y*y1 + ga.z*y2 + ga.w*y3;
      acc4.y -= gb.x*y0 + gb.y*y1 + gb.z*y2 + gb.w*y3;
      acc4.z -= gc.x*y0 + gc.y*y1 + gc.z*y2 + gc.w*y3;
      acc4.w -= gd.x*y0 + gd.y*y1 + gd.z*y2 + gd.w*y3;
      *(float4*)&pool[(jb + (g ^ jx)) * 4] = acc4;
    }
  }
  __syncthreads();   // all vO chunk reads done (also y rows complete)
  for (int s4 = 0; s4 < 16; ++s4) {
    float4 yy = *(const float4*)&pool[(jb + (s4 ^ jx)) * 4];
    float z0 = (gT / gam[s4*4+0]) * yy.x;
    float z1 = (gT / gam[s4*4+1]) * yy.y;
    float z2 = (gT / gam[s4*4+2]) * yy.z;
    float z3 = (gT / gam[s4*4+3]) * yy.w;
    *(float4*)&vO[base + (size_t)j*64 + s4*4] = make_float4(z0, z1, z2, z3);  // Z^T [i][s]
  }

  // ---- O_intra: wX regs scaled to Omega, t-blocked by 8 (R24) ----
  {
    const float gaml = gam[lane];
    float4 wX[16];
    #pragma unroll
    for (int s4 = 0; s4 < 16; ++s4) {
      float4 wv = *(const float4*)&Wl[lane][s4*4];
      wv.x *= gaml / gam[s4*4+0];
      wv.y *= gaml / gam[s4*4+1];
      wv.z *= gaml / gam[s4*4+2];
      wv.w *= gaml / gam[s4*4+3];
      wX[s4] = wv;
    }
    for (int tb = 0; tb < 8; ++tb) {
      float acc[8];
      #pragma unroll
      for (int i = 0; i < 8; ++i) acc[i] = 0.f;
      #pragma unroll
      for (int s4 = 0; s4 < 16; ++s4) {
        float4 yy = *(const float4*)&pool[(jb + (s4 ^ jx)) * 4];
        #pragma unroll
        for (int i = 0; i < 8; ++i) {
          const int t = tb*8 + i;
          acc[i] += rdlane(wX[s4].x, t) * yy.x
                  + rdlane(wX[s4].y, t) * yy.y
                  + rdlane(wX[s4].z, t) * yy.z
                  + rdlane(wX[s4].w, t) * yy.w;
        }
      }
      #pragma unroll
      for (int i = 0; i < 8; ++i)
        Oout[base + (size_t)(tb*8 + i)*C_ + j] = acc[i];
    }
  }
}

// ---------------- serial chunk scan v4 (R22 verbatim) ----------------------
__global__ __launch_bounds__(512) void chunk_scan(const float* __restrict__ kn,
                                                  const float* __restrict__ qrm,
                                                  const float* __restrict__ urm,
                                                  const float* __restrict__ ztT,
                                                  const float* __restrict__ gbuf,
                                                  float* __restrict__ Oout) {
  __shared__ float Qs[16384];
  __shared__ float Us[16384];
  __shared__ float red[8*64*12];
  const int bid = blockIdx.x;
  const int b = bid & 7;
  const int wgrp = bid >> 3;
  const int tid = threadIdx.x;
  const int wave = tid >> 6, lane = tid & 63;
  const int half = wave >> 2, jq = wave & 3;
  const int i0h = wgrp*8 + half*4;
  const int lx = lane & 15;

  float S_[4];
  #pragma unroll
  for (int r = 0; r < 4; ++r) S_[r] = 0.f;

  for (int ch = 0; ch < NCH; ++ch) {
    const size_t ct0 = (size_t)b*N_ + (size_t)ch*T_;
    const size_t base = ct0 * C_;

    #pragma unroll
    for (int i = 0; i < 8; ++i) {
      int g = i*512 + tid;
      int t = g >> 6, u = g & 63;
      int phys = (t*64 + (u ^ (t & 15))) * 4;
      *(float4*)&Qs[phys] = *(const float4*)(qrm + base + (size_t)g*4);
      *(float4*)&Us[phys] = *(const float4*)(urm + base + (size_t)g*4);
    }
    __syncthreads();                               // B1

    const float gv = gbuf[ct0 + lane];
    const float gT = rdlane(gv, 63);

    float oA[4], dB[4];
    #pragma unroll
    for (int r = 0; r < 4; ++r) { oA[r] = 0.f; dB[r] = 0.f; }
    #pragma unroll
    for (int uu = 0; uu < 16; ++uu) {
      const int u = (jq << 4) + uu;
      float4 qv = *(const float4*)&Qs[(lane*64 + (u ^ lx)) * 4];
      float4 uv = *(const float4*)&Us[(lane*64 + (u ^ lx)) * 4];
      #pragma unroll
      for (int m = 0; m < 4; ++m) {
        const int jl = 4*uu + m;
        const float qm = (m==0) ? qv.x : (m==1) ? qv.y : (m==2) ? qv.z : qv.w;
        const float um = (m==0) ? uv.x : (m==1) ? uv.y : (m==2) ? uv.z : uv.w;
        #pragma unroll
        for (int r = 0; r < 4; ++r) {
          const float sv = rdlane(S_[r], jl);
          oA[r] += sv * qm;
          dB[r] += sv * um;
        }
      }
    }
    {
      float* rp = &red[(wave*64 + lane) * 12];
      *(float4*)&rp[0] = make_float4(oA[0], oA[1], oA[2], oA[3]);
      *(float4*)&rp[4] = make_float4(dB[0], dB[1], dB[2], dB[3]);
    }
    __syncthreads();                               // B2

    #pragma unroll
    for (int i = 0; i < 8; ++i) {
      int idx = (i*512 + tid) * 4;
      *(float4*)&Qs[idx] = *(const float4*)(kn + base + idx);
    }

    #pragma unroll
    for (int r = 0; r < 4; ++r) { oA[r] = 0.f; dB[r] = 0.f; }
    #pragma unroll
    for (int jq2 = 0; jq2 < 4; ++jq2) {
      const float* rp = &red[((half*4 + jq2)*64 + lane) * 12];
      float4 a = *(const float4*)&rp[0];
      float4 d = *(const float4*)&rp[4];
      oA[0] += a.x; oA[1] += a.y; oA[2] += a.z; oA[3] += a.w;
      dB[0] += d.x; dB[1] += d.y; dB[2] += d.z; dB[3] += d.w;
    }
    #pragma unroll
    for (int r = 0; r < 4; ++r) {
      const float z = ztT[base + (size_t)(i0h + r)*64 + lane];
      dB[r] = gT*dB[r] - z;
    }
    if (jq == 0) {
      float* orow = Oout + base + (size_t)lane*C_ + i0h;
      float4 o0 = *(float4*)&orow[0];
      o0.x += gv*oA[0]; o0.y += gv*oA[1]; o0.z += gv*oA[2]; o0.w += gv*oA[3];
      *(float4*)&orow[0] = o0;
    }
    __syncthreads();                               // B3

    float acc[4];
    #pragma unroll
    for (int r = 0; r < 4; ++r) acc[r] = 0.f;
    const int jcol = (jq << 6) + lane;
    #pragma unroll 8
    for (int s = 0; s < 64; ++s) {
      const float kv = Qs[s*256 + jcol];
      #pragma unroll
      for (int r = 0; r < 4; ++r)
        acc[r] += rdlane(dB[r], s) * kv;
    }
    #pragma unroll
    for (int r = 0; r < 4; ++r) S_[r] = gT*S_[r] - acc[r];
    __syncthreads();                               // B4
  }
}

extern "C" void kernel_launch(void* const* d_in, const int* in_sizes, int n_in,
                              void* d_out, int out_size, void* d_ws, size_t ws_size,
                              hipStream_t stream) {
  const float* x  = (const float*)d_in[0];
  const float* Wq = (const float*)d_in[1];  const float* bq = (const float*)d_in[2];
  const float* Wk = (const float*)d_in[3];  const float* bk = (const float*)d_in[4];
  const float* Wv = (const float*)d_in[5];  const float* bv = (const float*)d_in[6];
  const float* Wa = (const float*)d_in[7];  const float* ba = (const float*)d_in[8];
  const float* Wb = (const float*)d_in[9];  const float* bb = (const float*)d_in[10];
  const float* Wo = (const float*)d_in[11]; const float* bo = (const float*)d_in[12];

  float* ws = (float*)d_ws;
  const size_t TC = (size_t)TOK * C_;
  float* qn   = ws;
  float* kn   = ws + TC;
  float* vO   = ws + 2*TC;             // V -> Z^T [i][s] (in place)
  float* Ag   = ws + 3*TC;
  float* Bg   = Ag + TOK;
  float* gbuf = Bg + TOK;
  float* Ubuf = gbuf + TOK;            // x-splits -> U -> Wo-splits
  float* qrm  = Ubuf + TC;             // Qtilde -> O-splits

  unsigned short* xhi = (unsigned short*)Ubuf;
  unsigned short* xlo = xhi + TC;
  unsigned short* whd = (unsigned short*)d_out;
  unsigned short* whiU = (unsigned short*)Ubuf;
  unsigned short* wloU = whiU + 65536;
  unsigned short* ohi = (unsigned short*)qrm;
  unsigned short* olo = ohi + TC;

  split_pack<<<dim3(TC/1024), 256, 0, stream>>>(x, xhi, xlo);
  split_pack<<<dim3(64), 256, 0, stream>>>(Wq, whd + 0*131072, whd + 0*131072 + 65536);
  split_pack<<<dim3(64), 256, 0, stream>>>(Wk, whd + 1*131072, whd + 1*131072 + 65536);
  split_pack<<<dim3(64), 256, 0, stream>>>(Wv, whd + 2*131072, whd + 2*131072 + 65536);
  split_pack<<<dim3(64), 256, 0, stream>>>(Wa, whd + 3*131072, whd + 3*131072 + 65536);
  split_pack<<<dim3(64), 256, 0, stream>>>(Wb, whd + 4*131072, whd + 4*131072 + 65536);
  proj_v3<0><<<dim3(TOK/16), 256, 0, stream>>>(xhi, xlo, whd + 0*131072, whd + 0*131072 + 65536, bq, qn);
  proj_v3<0><<<dim3(TOK/16), 256, 0, stream>>>(xhi, xlo, whd + 1*131072, whd + 1*131072 + 65536, bk, kn);
  proj_v3<1><<<dim3(TOK/16), 256, 0, stream>>>(xhi, xlo, whd + 2*131072, whd + 2*131072 + 65536, bv, vO);
  proj_v3<2><<<dim3(TOK/16), 256, 0, stream>>>(xhi, xlo, whd + 3*131072, whd + 3*131072 + 65536, ba, Ag);
  proj_v3<2><<<dim3(TOK/16), 256, 0, stream>>>(xhi, xlo, whd + 4*131072, whd + 4*131072 + 65536, bb, Bg);
  chunk_prep<<<dim3(256), 256, 0, stream>>>(kn, qn, vO, Ag, Bg, Ubuf, qrm, gbuf,
                                            (float*)d_out);
  chunk_scan<<<dim3(256), 512, 0, stream>>>(kn, qrm, Ubuf, vO, gbuf,
                                            (float*)d_out);
  split_pack<<<dim3(64), 256, 0, stream>>>(Wo, whiU, wloU);
  split_pack<<<dim3(TC/1024), 256, 0, stream>>>((const float*)d_out, ohi, olo);
  proj_v3<3><<<dim3(TOK/16), 256, 0, stream>>>(ohi, olo, whiU, wloU, bo,
                                               (float*)d_out);
}

// Round 28
// 523.060 us; speedup vs baseline: 1.0906x; 1.0018x over previous
//
#include <hip/hip_runtime.h>
#include <math.h>

#define B_ 8
#define N_ 2048
#define C_ 256
#define TOK (B_*N_)
#define T_ 64
#define NCH (N_/T_)   // 32 chunks per batch

typedef __bf16 bf16x8 __attribute__((ext_vector_type(8)));
typedef float f32x4v __attribute__((ext_vector_type(4)));

__device__ __forceinline__ float dot4(const float4& a, const float4& b) {
  return (a.x*b.x + a.y*b.y) + (a.z*b.z + a.w*b.w);
}
__device__ __forceinline__ float rdlane(float x, int idx) {
  return __int_as_float(__builtin_amdgcn_readlane(__float_as_int(x), idx));
}
__device__ __forceinline__ float bf2f(unsigned short u) {
  return __uint_as_float(((unsigned)u) << 16);
}
__device__ __forceinline__ unsigned short f2bf(float f) {
  unsigned x = __float_as_uint(f);
  return (unsigned short)((x + 0x7FFFu + ((x >> 16) & 1u)) >> 16);
}

// ---------------- bf16 hi/lo split, FRAGMENT-PACKED ------------------------
__global__ __launch_bounds__(256) void split_pack(const float* __restrict__ src,
                                                  unsigned short* __restrict__ hi,
                                                  unsigned short* __restrict__ lo) {
  const size_t f = ((size_t)blockIdx.x * 256 + threadIdx.x) * 4;
  float4 v = *(const float4*)(src + f);
  const int row = (int)(f >> 8);
  const int k   = (int)(f & 255);
  const int R = row >> 4, lr = row & 15;
  const int ks = k >> 5, kg = (k >> 3) & 3, ki = k & 7;
  const size_t pos = ((((size_t)R*8 + ks)*64) + kg*16 + lr)*8 + ki;
  ushort4 H, L;
  H.x = f2bf(v.x); H.y = f2bf(v.y); H.z = f2bf(v.z); H.w = f2bf(v.w);
  L.x = f2bf(v.x - bf2f(H.x));
  L.y = f2bf(v.y - bf2f(H.y));
  L.z = f2bf(v.z - bf2f(H.z));
  L.w = f2bf(v.w - bf2f(H.w));
  *(ushort4*)(hi + pos) = H;
  *(ushort4*)(lo + pos) = L;
}

// ---------------- MFMA projection v3: packed fragments ---------------------
template<int EPI>  // 0 silu+l2norm, 1 silu, 2 sigmoid+mean, 3 bias-only
__global__ __launch_bounds__(256) void proj_v3(const unsigned short* __restrict__ xh,
                                               const unsigned short* __restrict__ xl,
                                               const unsigned short* __restrict__ wh,
                                               const unsigned short* __restrict__ wl,
                                               const float* __restrict__ bias,
                                               float* __restrict__ out) {
  __shared__ float redp[4][20];
  const int tid = threadIdx.x;
  const int l = tid & 63, w = tid >> 6;
  const int lc = l & 15, kg = l >> 4;
  const int rb = blockIdx.x * 16;
  const size_t Rbase = (size_t)blockIdx.x * 8;

  f32x4v acc[4];
  #pragma unroll
  for (int nt2 = 0; nt2 < 4; ++nt2) acc[nt2] = (f32x4v){0.f, 0.f, 0.f, 0.f};

  #pragma unroll
  for (int ks = 0; ks < 8; ++ks) {
    const size_t apos = ((Rbase + ks)*64 + l)*8;
    bf16x8 ah = *reinterpret_cast<const bf16x8*>(xh + apos);
    bf16x8 al = *reinterpret_cast<const bf16x8*>(xl + apos);
    #pragma unroll
    for (int nt2 = 0; nt2 < 4; ++nt2) {
      const size_t bpos = (((size_t)(w*4 + nt2)*8 + ks)*64 + l)*8;
      bf16x8 bh = *reinterpret_cast<const bf16x8*>(wh + bpos);
      bf16x8 bl = *reinterpret_cast<const bf16x8*>(wl + bpos);
      acc[nt2] = __builtin_amdgcn_mfma_f32_16x16x32_bf16(ah, bh, acc[nt2], 0, 0, 0);
      acc[nt2] = __builtin_amdgcn_mfma_f32_16x16x32_bf16(ah, bl, acc[nt2], 0, 0, 0);
      acc[nt2] = __builtin_amdgcn_mfma_f32_16x16x32_bf16(al, bh, acc[nt2], 0, 0, 0);
    }
  }

  const int row0 = kg * 4;

  if constexpr (EPI == 3) {
    #pragma unroll
    for (int nt2 = 0; nt2 < 4; ++nt2) {
      const float bval = bias[w*64 + nt2*16 + lc];
      #pragma unroll
      for (int e = 0; e < 4; ++e)
        out[(size_t)(rb + row0 + e)*C_ + w*64 + nt2*16 + lc] = acc[nt2][e] + bval;
    }
  } else if constexpr (EPI == 1) {
    #pragma unroll
    for (int nt2 = 0; nt2 < 4; ++nt2) {
      const float bval = bias[w*64 + nt2*16 + lc];
      #pragma unroll
      for (int e = 0; e < 4; ++e) {
        float y = acc[nt2][e] + bval;
        out[(size_t)(rb + row0 + e)*C_ + w*64 + nt2*16 + lc] = y / (1.f + __expf(-y));
      }
    }
  } else if constexpr (EPI == 0) {
    float part[4] = {0.f, 0.f, 0.f, 0.f};
    #pragma unroll
    for (int nt2 = 0; nt2 < 4; ++nt2) {
      const float bval = bias[w*64 + nt2*16 + lc];
      #pragma unroll
      for (int e = 0; e < 4; ++e) {
        float y = acc[nt2][e] + bval;
        float s = y / (1.f + __expf(-y));
        acc[nt2][e] = s;
        part[e] += s * s;
      }
    }
    #pragma unroll
    for (int e = 0; e < 4; ++e) {
      float r = part[e];
      r += __shfl_xor(r, 1, 64);
      r += __shfl_xor(r, 2, 64);
      r += __shfl_xor(r, 4, 64);
      r += __shfl_xor(r, 8, 64);
      part[e] = r;
    }
    if (lc == 0) {
      #pragma unroll
      for (int e = 0; e < 4; ++e) redp[w][row0 + e] = part[e];
    }
    __syncthreads();
    #pragma unroll
    for (int e = 0; e < 4; ++e) {
      float s = redp[0][row0+e] + redp[1][row0+e] + redp[2][row0+e] + redp[3][row0+e];
      part[e] = 1.f / (sqrtf(s) + 1e-6f);
    }
    #pragma unroll
    for (int nt2 = 0; nt2 < 4; ++nt2)
      #pragma unroll
      for (int e = 0; e < 4; ++e)
        out[(size_t)(rb + row0 + e)*C_ + w*64 + nt2*16 + lc] = acc[nt2][e] * part[e];
  } else {
    float part[4] = {0.f, 0.f, 0.f, 0.f};
    #pragma unroll
    for (int nt2 = 0; nt2 < 4; ++nt2) {
      const float bval = bias[w*64 + nt2*16 + lc];
      #pragma unroll
      for (int e = 0; e < 4; ++e) {
        float y = acc[nt2][e] + bval;
        part[e] += 1.f / (1.f + __expf(-y));
      }
    }
    #pragma unroll
    for (int e = 0; e < 4; ++e) {
      float r = part[e];
      r += __shfl_xor(r, 1, 64);
      r += __shfl_xor(r, 2, 64);
      r += __shfl_xor(r, 4, 64);
      r += __shfl_xor(r, 8, 64);
      part[e] = r;
    }
    if (lc == 0) {
      #pragma unroll
      for (int e = 0; e < 4; ++e) redp[w][row0 + e] = part[e];
    }
    __syncthreads();
    if (w == 0 && lc == 0) {
      #pragma unroll
      for (int e = 0; e < 4; ++e) {
        float s = redp[0][row0+e] + redp[1][row0+e] + redp[2][row0+e] + redp[3][row0+e];
        out[rb + row0 + e] = s * (1.f / 256.f);
      }
    }
  }
}

// ---------------- fused gram + WY solves + intra output --------------------
// R25 math. DATAFLOW CHANGE (determinism hardening): O_intra is written into
// the qn buffer (dead after this block's gram/Qtilde reads, which all
// precede the write) instead of d_out. qn is a single non-restrict pointer
// used for both the reads and the late O_intra write (no UB aliasing).
__global__ __launch_bounds__(256) void chunk_prep(const float* __restrict__ kn,
                                                  float* qn,            // read Q, late-write O_intra
                                                  float* __restrict__ vO,
                                                  const float* __restrict__ Ag,
                                                  const float* __restrict__ Bg,
                                                  float* __restrict__ Ubuf,
                                                  float* __restrict__ qrm,
                                                  float* __restrict__ gbuf) {
  __shared__ float Gl[64][68];
  __shared__ float Wl[64][68];
  __shared__ float pool[17408];
  __shared__ float gam[64], al[64], bl[64];
  float* Kp = pool;
  float* Qp = pool + 4096;
  const int bid = blockIdx.x;
  const int b = bid & 7, c = bid >> 3;
  const size_t ct0 = (size_t)b*N_ + (size_t)c*T_;
  const size_t base = ct0 * C_;
  const int tid = threadIdx.x;
  const int lane = tid & 63;
  const int sg = tid >> 6;

  if (tid < 64) { al[tid] = Ag[ct0 + tid]; bl[tid] = Bg[ct0 + tid]; }

  float accG[16], accQ[16];
  #pragma unroll
  for (int m = 0; m < 16; ++m) { accG[m] = 0.f; accQ[m] = 0.f; }
  for (int p = 0; p < 4; ++p) {
    __syncthreads();
    #pragma unroll
    for (int i = 0; i < 4; ++i) {
      int idx = i*256 + tid;
      int t = idx >> 4, u = idx & 15;
      int phys = (t*16 + (u ^ (t & 15))) * 4;
      *(float4*)&Kp[phys] = *(const float4*)(kn + base + (size_t)t*C_ + p*64 + u*4);
      *(float4*)&Qp[phys] = *(const float4*)(qn + base + (size_t)t*C_ + p*64 + u*4);
    }
    __syncthreads();
    #pragma unroll 4
    for (int j4 = 0; j4 < 16; ++j4) {
      float4 kt = *(const float4*)&Kp[(lane*16 + (j4 ^ (lane & 15))) * 4];
      float4 qt = *(const float4*)&Qp[(lane*16 + (j4 ^ (lane & 15))) * 4];
      #pragma unroll
      for (int m = 0; m < 16; ++m) {
        int r = sg*16 + m;
        float4 ks = *(const float4*)&Kp[(r*16 + (j4 ^ (r & 15))) * 4];
        accG[m] += dot4(kt, ks);
        accQ[m] += dot4(qt, ks);
      }
    }
  }
  __syncthreads();
  #pragma unroll
  for (int m = 0; m < 16; ++m) {
    int col = sg*16 + m;
    Gl[lane][col] = (col <  lane) ? accG[m] : 0.f;
    Wl[lane][col] = (col <= lane) ? accQ[m] : 0.f;
  }
  __syncthreads();
  if (tid == 0) {
    float g = 1.f;
    for (int s = 0; s < 64; ++s) { g *= al[s]; gam[s] = g; }
  }
  __syncthreads();
  if (tid < 64) gbuf[ct0 + tid] = gam[tid];
  __syncthreads();   // gram reads of pool done before rows overwrite it

  const int j = tid;
  const int jx = j & 15;
  const int jb = j * 16;   // float4-unit base of this thread's row

  // ---- U solve: preload kn column, blocked rank-4 substitution ----
  #pragma unroll
  for (int s4 = 0; s4 < 16; ++s4) {
    float4 kv;
    kv.x = kn[base + (size_t)(s4*4+0)*C_ + j];
    kv.y = kn[base + (size_t)(s4*4+1)*C_ + j];
    kv.z = kn[base + (size_t)(s4*4+2)*C_ + j];
    kv.w = kn[base + (size_t)(s4*4+3)*C_ + j];
    *(float4*)&pool[(jb + (s4 ^ jx)) * 4] = kv;
  }
  for (int bq = 0; bq < 16; ++bq) {
    const int s0 = bq * 4;
    float4 a = *(const float4*)&pool[(jb + (bq ^ jx)) * 4];
    float4 g1 = *(const float4*)&Gl[s0+1][s0];
    float4 g2 = *(const float4*)&Gl[s0+2][s0];
    float4 g3 = *(const float4*)&Gl[s0+3][s0];
    float u0 = bl[s0+0] * a.x;
    float u1 = bl[s0+1] * (a.y - g1.x*u0);
    float u2 = bl[s0+2] * (a.z - g2.x*u0 - g2.y*u1);
    float u3 = bl[s0+3] * (a.w - g3.x*u0 - g3.y*u1 - g3.z*u2);
    *(float4*)&pool[(jb + (bq ^ jx)) * 4] = make_float4(u0, u1, u2, u3);
    Ubuf[base + (size_t)(s0+0)*C_ + j] = u0;
    Ubuf[base + (size_t)(s0+1)*C_ + j] = u1;
    Ubuf[base + (size_t)(s0+2)*C_ + j] = u2;
    Ubuf[base + (size_t)(s0+3)*C_ + j] = u3;
    for (int g = bq + 1; g < 16; ++g) {   // independent rank-4 updates
      float4 acc4 = *(const float4*)&pool[(jb + (g ^ jx)) * 4];
      float4 ga = *(const float4*)&Gl[4*g+0][s0];
      float4 gb = *(const float4*)&Gl[4*g+1][s0];
      float4 gc = *(const float4*)&Gl[4*g+2][s0];
      float4 gd = *(const float4*)&Gl[4*g+3][s0];
      acc4.x -= ga.x*u0 + ga.y*u1 + ga.z*u2 + ga.w*u3;
      acc4.y -= gb.x*u0 + gb.y*u1 + gb.z*u2 + gb.w*u3;
      acc4.z -= gc.x*u0 + gc.y*u1 + gc.z*u2 + gc.w*u3;
      acc4.w -= gd.x*u0 + gd.y*u1 + gd.z*u2 + gd.w*u3;
      *(float4*)&pool[(jb + (g ^ jx)) * 4] = acc4;
    }
  }

  // ---- Qtilde: wX registers + readlane, t-blocked by 8 ----
  {
    float4 wX[16];
    #pragma unroll
    for (int s4 = 0; s4 < 16; ++s4) wX[s4] = *(const float4*)&Wl[lane][s4*4];
    for (int tb = 0; tb < 8; ++tb) {
      float acc[8];
      #pragma unroll
      for (int i = 0; i < 8; ++i)
        acc[i] = qn[base + (size_t)(tb*8 + i)*C_ + j];
      #pragma unroll
      for (int s4 = 0; s4 < 16; ++s4) {
        float4 uu = *(const float4*)&pool[(jb + (s4 ^ jx)) * 4];
        #pragma unroll
        for (int i = 0; i < 8; ++i) {
          const int t = tb*8 + i;
          acc[i] -= rdlane(wX[s4].x, t) * uu.x
                  + rdlane(wX[s4].y, t) * uu.y
                  + rdlane(wX[s4].z, t) * uu.z
                  + rdlane(wX[s4].w, t) * uu.w;
        }
      }
      #pragma unroll
      for (int i = 0; i < 8; ++i)
        qrm[base + (size_t)(tb*8 + i)*C_ + j] = acc[i];
    }
  }

  // ---- scale: Gl -> Ghat only ----
  __syncthreads();
  #pragma unroll
  for (int p2 = 0; p2 < 16; ++p2) {
    int idx = p2*256 + tid; int s = idx >> 6, r = idx & 63;
    Gl[s][r] *= gam[s] / gam[r];
  }
  __syncthreads();
  const float gT = gam[63];

  // ---- Y solve: preload vO column, blocked rank-4 substitution ----
  #pragma unroll
  for (int s4 = 0; s4 < 16; ++s4) {
    float4 vv;
    vv.x = vO[base + (size_t)(s4*4+0)*C_ + j];
    vv.y = vO[base + (size_t)(s4*4+1)*C_ + j];
    vv.z = vO[base + (size_t)(s4*4+2)*C_ + j];
    vv.w = vO[base + (size_t)(s4*4+3)*C_ + j];
    *(float4*)&pool[(jb + (s4 ^ jx)) * 4] = vv;
  }
  for (int bq = 0; bq < 16; ++bq) {
    const int s0 = bq * 4;
    float4 a = *(const float4*)&pool[(jb + (bq ^ jx)) * 4];
    float4 g1 = *(const float4*)&Gl[s0+1][s0];
    float4 g2 = *(const float4*)&Gl[s0+2][s0];
    float4 g3 = *(const float4*)&Gl[s0+3][s0];
    float y0 = bl[s0+0] * a.x;
    float y1 = bl[s0+1] * (a.y - g1.x*y0);
    float y2 = bl[s0+2] * (a.z - g2.x*y0 - g2.y*y1);
    float y3 = bl[s0+3] * (a.w - g3.x*y0 - g3.y*y1 - g3.z*y2);
    *(float4*)&pool[(jb + (bq ^ jx)) * 4] = make_float4(y0, y1, y2, y3);
    for (int g = bq + 1; g < 16; ++g) {
      float4 acc4 = *(const float4*)&pool[(jb + (g ^ jx)) * 4];
      float4 ga = *(const float4*)&Gl[4*g+0][s0];
      float4 gb = *(const float4*)&Gl[4*g+1][s0];
      float4 gc = *(const float4*)&Gl[4*g+2][s0];
      float4 gd = *(const float4*)&Gl[4*g+3][s0];
      acc4.x -= ga.x*y0 + ga.y*y1 + ga.z*y2 + ga.w*y3;
      acc4.y -= gb.x*y0 + gb.y*y1 + gb.z*y2 + gb.w*y3;
      acc4.z -= gc.x*y0 + gc.y*y1 + gc.z*y2 + gc.w*y3;
      acc4.w -= gd.x*y0 + gd.y*y1 + gd.z*y2 + gd.w*y3;
      *(float4*)&pool[(jb + (g ^ jx)) * 4] = acc4;
    }
  }
  __syncthreads();   // all vO and qn chunk reads done (also y rows complete)
  for (int s4 = 0; s4 < 16; ++s4) {
    float4 yy = *(const float4*)&pool[(jb + (s4 ^ jx)) * 4];
    float z0 = (gT / gam[s4*4+0]) * yy.x;
    float z1 = (gT / gam[s4*4+1]) * yy.y;
    float z2 = (gT / gam[s4*4+2]) * yy.z;
    float z3 = (gT / gam[s4*4+3]) * yy.w;
    *(float4*)&vO[base + (size_t)j*64 + s4*4] = make_float4(z0, z1, z2, z3);  // Z^T [i][s]
  }

  // ---- O_intra -> qn (dead now; all qn reads of this chunk completed) ----
  {
    const float gaml = gam[lane];
    float4 wX[16];
    #pragma unroll
    for (int s4 = 0; s4 < 16; ++s4) {
      float4 wv = *(const float4*)&Wl[lane][s4*4];
      wv.x *= gaml / gam[s4*4+0];
      wv.y *= gaml / gam[s4*4+1];
      wv.z *= gaml / gam[s4*4+2];
      wv.w *= gaml / gam[s4*4+3];
      wX[s4] = wv;
    }
    for (int tb = 0; tb < 8; ++tb) {
      float acc[8];
      #pragma unroll
      for (int i = 0; i < 8; ++i) acc[i] = 0.f;
      #pragma unroll
      for (int s4 = 0; s4 < 16; ++s4) {
        float4 yy = *(const float4*)&pool[(jb + (s4 ^ jx)) * 4];
        #pragma unroll
        for (int i = 0; i < 8; ++i) {
          const int t = tb*8 + i;
          acc[i] += rdlane(wX[s4].x, t) * yy.x
                  + rdlane(wX[s4].y, t) * yy.y
                  + rdlane(wX[s4].z, t) * yy.z
                  + rdlane(wX[s4].w, t) * yy.w;
        }
      }
      #pragma unroll
      for (int i = 0; i < 8; ++i)
        qn[base + (size_t)(tb*8 + i)*C_ + j] = acc[i];
    }
  }
}

// ---------------- serial chunk scan: PURE-WRITE output ---------------------
// R22 structure; O phase reads O_intra from oint (= qn) and WRITES the full
// output to Oout (= d_out). d_out is never read -> no cross-kernel RMW.
__global__ __launch_bounds__(512) void chunk_scan(const float* __restrict__ kn,
                                                  const float* __restrict__ qrm,
                                                  const float* __restrict__ urm,
                                                  const float* __restrict__ ztT,
                                                  const float* __restrict__ gbuf,
                                                  const float* __restrict__ oint,
                                                  float* __restrict__ Oout) {
  __shared__ float Qs[16384];
  __shared__ float Us[16384];
  __shared__ float red[8*64*12];
  const int bid = blockIdx.x;
  const int b = bid & 7;
  const int wgrp = bid >> 3;
  const int tid = threadIdx.x;
  const int wave = tid >> 6, lane = tid & 63;
  const int half = wave >> 2, jq = wave & 3;
  const int i0h = wgrp*8 + half*4;
  const int lx = lane & 15;

  float S_[4];
  #pragma unroll
  for (int r = 0; r < 4; ++r) S_[r] = 0.f;

  for (int ch = 0; ch < NCH; ++ch) {
    const size_t ct0 = (size_t)b*N_ + (size_t)ch*T_;
    const size_t base = ct0 * C_;

    #pragma unroll
    for (int i = 0; i < 8; ++i) {
      int g = i*512 + tid;
      int t = g >> 6, u = g & 63;
      int phys = (t*64 + (u ^ (t & 15))) * 4;
      *(float4*)&Qs[phys] = *(const float4*)(qrm + base + (size_t)g*4);
      *(float4*)&Us[phys] = *(const float4*)(urm + base + (size_t)g*4);
    }
    __syncthreads();                               // B1

    const float gv = gbuf[ct0 + lane];
    const float gT = rdlane(gv, 63);

    float oA[4], dB[4];
    #pragma unroll
    for (int r = 0; r < 4; ++r) { oA[r] = 0.f; dB[r] = 0.f; }
    #pragma unroll
    for (int uu = 0; uu < 16; ++uu) {
      const int u = (jq << 4) + uu;
      float4 qv = *(const float4*)&Qs[(lane*64 + (u ^ lx)) * 4];
      float4 uv = *(const float4*)&Us[(lane*64 + (u ^ lx)) * 4];
      #pragma unroll
      for (int m = 0; m < 4; ++m) {
        const int jl = 4*uu + m;
        const float qm = (m==0) ? qv.x : (m==1) ? qv.y : (m==2) ? qv.z : qv.w;
        const float um = (m==0) ? uv.x : (m==1) ? uv.y : (m==2) ? uv.z : uv.w;
        #pragma unroll
        for (int r = 0; r < 4; ++r) {
          const float sv = rdlane(S_[r], jl);
          oA[r] += sv * qm;
          dB[r] += sv * um;
        }
      }
    }
    {
      float* rp = &red[(wave*64 + lane) * 12];
      *(float4*)&rp[0] = make_float4(oA[0], oA[1], oA[2], oA[3]);
      *(float4*)&rp[4] = make_float4(dB[0], dB[1], dB[2], dB[3]);
    }
    __syncthreads();                               // B2

    #pragma unroll
    for (int i = 0; i < 8; ++i) {
      int idx = (i*512 + tid) * 4;
      *(float4*)&Qs[idx] = *(const float4*)(kn + base + idx);
    }

    #pragma unroll
    for (int r = 0; r < 4; ++r) { oA[r] = 0.f; dB[r] = 0.f; }
    #pragma unroll
    for (int jq2 = 0; jq2 < 4; ++jq2) {
      const float* rp = &red[((half*4 + jq2)*64 + lane) * 12];
      float4 a = *(const float4*)&rp[0];
      float4 d = *(const float4*)&rp[4];
      oA[0] += a.x; oA[1] += a.y; oA[2] += a.z; oA[3] += a.w;
      dB[0] += d.x; dB[1] += d.y; dB[2] += d.z; dB[3] += d.w;
    }
    #pragma unroll
    for (int r = 0; r < 4; ++r) {
      const float z = ztT[base + (size_t)(i0h + r)*64 + lane];
      dB[r] = gT*dB[r] - z;
    }
    if (jq == 0) {
      const float* irow = oint + base + (size_t)lane*C_ + i0h;
      float* orow = Oout + base + (size_t)lane*C_ + i0h;
      float4 o0 = *(const float4*)&irow[0];   // O_intra from qn buffer
      o0.x += gv*oA[0]; o0.y += gv*oA[1]; o0.z += gv*oA[2]; o0.w += gv*oA[3];
      *(float4*)&orow[0] = o0;                // pure write to d_out
    }
    __syncthreads();                               // B3

    float acc[4];
    #pragma unroll
    for (int r = 0; r < 4; ++r) acc[r] = 0.f;
    const int jcol = (jq << 6) + lane;
    #pragma unroll 8
    for (int s = 0; s < 64; ++s) {
      const float kv = Qs[s*256 + jcol];
      #pragma unroll
      for (int r = 0; r < 4; ++r)
        acc[r] += rdlane(dB[r], s) * kv;
    }
    #pragma unroll
    for (int r = 0; r < 4; ++r) S_[r] = gT*S_[r] - acc[r];
    __syncthreads();                               // B4
  }
}

extern "C" void kernel_launch(void* const* d_in, const int* in_sizes, int n_in,
                              void* d_out, int out_size, void* d_ws, size_t ws_size,
                              hipStream_t stream) {
  const float* x  = (const float*)d_in[0];
  const float* Wq = (const float*)d_in[1];  const float* bq = (const float*)d_in[2];
  const float* Wk = (const float*)d_in[3];  const float* bk = (const float*)d_in[4];
  const float* Wv = (const float*)d_in[5];  const float* bv = (const float*)d_in[6];
  const float* Wa = (const float*)d_in[7];  const float* ba = (const float*)d_in[8];
  const float* Wb = (const float*)d_in[9];  const float* bb = (const float*)d_in[10];
  const float* Wo = (const float*)d_in[11]; const float* bo = (const float*)d_in[12];

  float* ws = (float*)d_ws;
  const size_t TC = (size_t)TOK * C_;
  float* qn   = ws;                    // Q -> O_intra (late in-kernel overwrite)
  float* kn   = ws + TC;
  float* vO   = ws + 2*TC;             // V -> Z^T [i][s] (in place)
  float* Ag   = ws + 3*TC;
  float* Bg   = Ag + TOK;
  float* gbuf = Bg + TOK;
  float* Ubuf = gbuf + TOK;            // x-splits -> U -> Wo-splits
  float* qrm  = Ubuf + TC;             // W-split scratch -> Qtilde -> O-splits

  unsigned short* xhi = (unsigned short*)Ubuf;
  unsigned short* xlo = xhi + TC;
  unsigned short* whd = (unsigned short*)qrm;      // 5 W-split pairs (scratch in qrm)
  unsigned short* whiU = (unsigned short*)Ubuf;    // Wo splits after scan
  unsigned short* wloU = whiU + 65536;
  unsigned short* ohi = (unsigned short*)qrm;      // O splits after scan
  unsigned short* olo = ohi + TC;

  split_pack<<<dim3(TC/1024), 256, 0, stream>>>(x, xhi, xlo);
  split_pack<<<dim3(64), 256, 0, stream>>>(Wq, whd + 0*131072, whd + 0*131072 + 65536);
  split_pack<<<dim3(64), 256, 0, stream>>>(Wk, whd + 1*131072, whd + 1*131072 + 65536);
  split_pack<<<dim3(64), 256, 0, stream>>>(Wv, whd + 2*131072, whd + 2*131072 + 65536);
  split_pack<<<dim3(64), 256, 0, stream>>>(Wa, whd + 3*131072, whd + 3*131072 + 65536);
  split_pack<<<dim3(64), 256, 0, stream>>>(Wb, whd + 4*131072, whd + 4*131072 + 65536);
  proj_v3<0><<<dim3(TOK/16), 256, 0, stream>>>(xhi, xlo, whd + 0*131072, whd + 0*131072 + 65536, bq, qn);
  proj_v3<0><<<dim3(TOK/16), 256, 0, stream>>>(xhi, xlo, whd + 1*131072, whd + 1*131072 + 65536, bk, kn);
  proj_v3<1><<<dim3(TOK/16), 256, 0, stream>>>(xhi, xlo, whd + 2*131072, whd + 2*131072 + 65536, bv, vO);
  proj_v3<2><<<dim3(TOK/16), 256, 0, stream>>>(xhi, xlo, whd + 3*131072, whd + 3*131072 + 65536, ba, Ag);
  proj_v3<2><<<dim3(TOK/16), 256, 0, stream>>>(xhi, xlo, whd + 4*131072, whd + 4*131072 + 65536, bb, Bg);
  chunk_prep<<<dim3(256), 256, 0, stream>>>(kn, qn, vO, Ag, Bg, Ubuf, qrm, gbuf);
  chunk_scan<<<dim3(256), 512, 0, stream>>>(kn, qrm, Ubuf, vO, gbuf, qn,
                                            (float*)d_out);
  split_pack<<<dim3(64), 256, 0, stream>>>(Wo, whiU, wloU);
  split_pack<<<dim3(TC/1024), 256, 0, stream>>>((const float*)d_out, ohi, olo);
  proj_v3<3><<<dim3(TOK/16), 256, 0, stream>>>(ohi, olo, whiU, wloU, bo,
                                               (float*)d_out);
}